// Round 1
// baseline (1418.506 us; speedup 1.0000x reference)
//
#include <hip/hip_runtime.h>
#include <math.h>

#define NN 1024
#define BB 64
#define LL 197
#define DD 768
#define NT 16
#define LCH 8

constexpr float LN_EPS = 1e-5f;
constexpr float NORM_EPS = 1e-12f;
constexpr float EPS = 1e-8f;

__device__ __forceinline__ float waveSum(float v) {
#pragma unroll
    for (int m = 32; m >= 1; m >>= 1) v += __shfl_xor(v, m, 64);
    return v;
}
__device__ __forceinline__ float waveMax(float v) {
#pragma unroll
    for (int m = 32; m >= 1; m >>= 1) v = fmaxf(v, __shfl_xor(v, m, 64));
    return v;
}

// Row LayerNorm; if qinv != nullptr also writes 1/max(||y||,1e-12) per row.
__global__ __launch_bounds__(256) void ln_kernel(
    const float* __restrict__ x, float* __restrict__ y,
    const float* __restrict__ gamma, const float* __restrict__ beta,
    float* __restrict__ qinv) {
    const int row = blockIdx.x;
    const int tid = threadIdx.x;
    const float* xr = x + (size_t)row * DD;
    float* yr = y + (size_t)row * DD;

    float v[3];
    float s = 0.f, ss = 0.f;
#pragma unroll
    for (int c = 0; c < 3; c++) {
        float t = xr[tid + 256 * c];
        v[c] = t; s += t; ss += t * t;
    }
    __shared__ float red[8];
    s = waveSum(s); ss = waveSum(ss);
    const int w = tid >> 6;
    if ((tid & 63) == 0) { red[w] = s; red[4 + w] = ss; }
    __syncthreads();
    s = red[0] + red[1] + red[2] + red[3];
    ss = red[4] + red[5] + red[6] + red[7];
    const float mean = s * (1.f / DD);
    const float var = ss * (1.f / DD) - mean * mean;
    const float rs = rsqrtf(var + LN_EPS);

    float q = 0.f;
#pragma unroll
    for (int c = 0; c < 3; c++) {
        const int d = tid + 256 * c;
        float t = (v[c] - mean) * rs * gamma[d] + beta[d];
        yr[d] = t;
        q += t * t;
    }
    if (qinv != nullptr) {
        __syncthreads();
        q = waveSum(q);
        if ((tid & 63) == 0) red[w] = q;
        __syncthreads();
        if (tid == 0) {
            float n2 = red[0] + red[1] + red[2] + red[3];
            qinv[row] = 1.f / fmaxf(sqrtf(n2), NORM_EPS);
        }
    }
}

// scores = tf . vt^T / sqrt(D), softmax over l, write attn [B,N,L].
// Block: (n-tile of 16, b). 256 threads = 4 waves; wave w owns rows w*4..w*4+3.
__global__ __launch_bounds__(256) void scores_kernel(
    const float* __restrict__ tf, const float* __restrict__ vt,
    float* __restrict__ attn) {
    const int b = blockIdx.y;
    const int n0 = blockIdx.x * NT;
    const int tid = threadIdx.x;
    const int w = tid >> 6, lane = tid & 63;

    __shared__ __align__(16) float vts[LCH][DD];     // 24 KB
    __shared__ __align__(16) float sl[NT][LL + 3];   // ~12.8 KB

    // tf fragments: 4 rows x 12 floats per lane (d = c*256 + lane*4 .. +3)
    float tfr[4][3][4];
#pragma unroll
    for (int j = 0; j < 4; j++) {
        const float* tr = tf + (size_t)(n0 + w * 4 + j) * DD;
#pragma unroll
        for (int c = 0; c < 3; c++) {
            const float4 t = *reinterpret_cast<const float4*>(tr + c * 256 + lane * 4);
            tfr[j][c][0] = t.x; tfr[j][c][1] = t.y; tfr[j][c][2] = t.z; tfr[j][c][3] = t.w;
        }
    }
    const float* vtb = vt + (size_t)b * LL * DD;
    const float scale = rsqrtf((float)DD);

    for (int lc = 0; lc < LL; lc += LCH) {
        const int nrows = min(LCH, LL - lc);
        __syncthreads();
        const int tot4 = nrows * DD / 4;
        for (int q = tid; q < tot4; q += 256) {
            float4 t = *reinterpret_cast<const float4*>(vtb + (size_t)lc * DD + (size_t)q * 4);
            *reinterpret_cast<float4*>(&vts[0][0] + (size_t)q * 4) = t;
        }
        __syncthreads();
        for (int li = 0; li < nrows; li++) {
            float p[4] = {0.f, 0.f, 0.f, 0.f};
#pragma unroll
            for (int c = 0; c < 3; c++) {
                const float4 vv = *reinterpret_cast<const float4*>(&vts[li][c * 256 + lane * 4]);
                const float va[4] = {vv.x, vv.y, vv.z, vv.w};
#pragma unroll
                for (int j = 0; j < 4; j++)
#pragma unroll
                    for (int k = 0; k < 4; k++)
                        p[j] += tfr[j][c][k] * va[k];
            }
#pragma unroll
            for (int j = 0; j < 4; j++) {
                float t = waveSum(p[j]);
                if (lane == 0) sl[w * 4 + j][lc + li] = t * scale;
            }
        }
    }
    __syncthreads();

    // softmax per row (wave w handles its own 4 rows)
#pragma unroll
    for (int j = 0; j < 4; j++) {
        const int row = w * 4 + j;
        float e[4];
        float m = -INFINITY;
#pragma unroll
        for (int k = 0; k < 4; k++) {
            const int l = lane + 64 * k;
            const float sv = (l < LL) ? sl[row][l] : -INFINITY;
            e[k] = sv;
            m = fmaxf(m, sv);
        }
        m = waveMax(m);
        float sum = 0.f;
#pragma unroll
        for (int k = 0; k < 4; k++) {
            const int l = lane + 64 * k;
            const float ev = (l < LL) ? expf(e[k] - m) : 0.f;
            e[k] = ev; sum += ev;
        }
        sum = waveSum(sum);
        const float inv = 1.f / sum;
        float* ar = attn + ((size_t)b * NN + n0 + row) * LL;
#pragma unroll
        for (int k = 0; k < 4; k++) {
            const int l = lane + 64 * k;
            if (l < LL) ar[l] = e[k] * inv;
        }
    }
}

// aggregated[b,n,:] = attn[b,n,:] . vt[b]; fused l2norm + logits[n,b] = qn.an
__global__ __launch_bounds__(256) void agg_kernel(
    const float* __restrict__ tf, const float* __restrict__ vt,
    const float* __restrict__ attn, const float* __restrict__ qinv,
    float* __restrict__ logits) {
    const int b = blockIdx.y;
    const int n0 = blockIdx.x * NT;
    const int tid = threadIdx.x;

    __shared__ __align__(16) float at[LL][NT];  // transposed attn tile, 12.6 KB
    for (int i = tid; i < NT * LL; i += 256) {
        const int nt = i / LL, l = i % LL;
        at[l][nt] = attn[((size_t)b * NN + n0 + nt) * LL + l];
    }
    __syncthreads();

    float acc[NT][3];
#pragma unroll
    for (int nt = 0; nt < NT; nt++)
#pragma unroll
        for (int c = 0; c < 3; c++) acc[nt][c] = 0.f;

    const float* vtb = vt + (size_t)b * LL * DD;
    for (int l = 0; l < LL; l++) {
        float va[3];
#pragma unroll
        for (int c = 0; c < 3; c++) va[c] = vtb[(size_t)l * DD + c * 256 + tid];
        const float4 a0 = *reinterpret_cast<const float4*>(&at[l][0]);
        const float4 a1 = *reinterpret_cast<const float4*>(&at[l][4]);
        const float4 a2 = *reinterpret_cast<const float4*>(&at[l][8]);
        const float4 a3 = *reinterpret_cast<const float4*>(&at[l][12]);
        const float av[NT] = {a0.x, a0.y, a0.z, a0.w, a1.x, a1.y, a1.z, a1.w,
                              a2.x, a2.y, a2.z, a2.w, a3.x, a3.y, a3.z, a3.w};
#pragma unroll
        for (int nt = 0; nt < NT; nt++)
#pragma unroll
            for (int c = 0; c < 3; c++)
                acc[nt][c] += av[nt] * va[c];
    }

    // per-row: ||agg||^2 and tf[n].agg
    __shared__ float r2[4][2 * NT];
    const int w = tid >> 6;
#pragma unroll
    for (int nt = 0; nt < NT; nt++) {
        float s1 = 0.f, s2 = 0.f;
#pragma unroll
        for (int c = 0; c < 3; c++) {
            const float a = acc[nt][c];
            s1 += a * a;
            s2 += a * tf[(size_t)(n0 + nt) * DD + c * 256 + tid];
        }
        s1 = waveSum(s1);
        s2 = waveSum(s2);
        if ((tid & 63) == 0) { r2[w][nt] = s1; r2[w][NT + nt] = s2; }
    }
    __syncthreads();
    if (tid < NT) {
        const float s1 = r2[0][tid] + r2[1][tid] + r2[2][tid] + r2[3][tid];
        const float s2 = r2[0][NT + tid] + r2[1][NT + tid] + r2[2][NT + tid] + r2[3][NT + tid];
        const float norm = fmaxf(sqrtf(s1), NORM_EPS);
        logits[(size_t)(n0 + tid) * BB + b] = qinv[n0 + tid] * s2 / norm;
    }
}

// per-row: scaled = exp(logits/temp), rowsum, pos, row_loss
__global__ __launch_bounds__(64) void loss_row_kernel(
    const float* __restrict__ logits, const int* __restrict__ gm,
    const float* __restrict__ logtemp, float* __restrict__ scaled,
    float* __restrict__ posv, float* __restrict__ rowloss) {
    const int n = blockIdx.x;
    const int b = threadIdx.x;  // 64 threads = B
    const float invtemp = 1.f / expf(logtemp[0]);
    const float e = expf(logits[(size_t)n * BB + b] * invtemp);
    scaled[(size_t)n * BB + b] = e;
    const float sum = waveSum(e);
    const int g = gm[n];
    const float pos = __shfl(e, g, 64);
    if (b == 0) {
        posv[n] = pos;
        rowloss[n] = -logf(pos / (sum + EPS) + EPS);
    }
}

__global__ __launch_bounds__(256) void colsum_kernel(
    const float* __restrict__ scaled, const int* __restrict__ gm,
    float* __restrict__ colsum, float* __restrict__ poscol) {
    const int b = blockIdx.x;
    const int tid = threadIdx.x;
    float s = 0.f, p = 0.f;
    for (int n = tid; n < NN; n += 256) {
        const float e = scaled[(size_t)n * BB + b];
        s += e;
        if (gm[n] == b) p += e;
    }
    s = waveSum(s); p = waveSum(p);
    __shared__ float red[8];
    const int w = tid >> 6;
    if ((tid & 63) == 0) { red[w] = s; red[4 + w] = p; }
    __syncthreads();
    if (tid == 0) {
        colsum[b] = red[0] + red[1] + red[2] + red[3];
        poscol[b] = red[4] + red[5] + red[6] + red[7];
    }
}

__global__ __launch_bounds__(1024) void final_kernel(
    const float* __restrict__ posv, const float* __restrict__ rowloss,
    const float* __restrict__ colsum, const float* __restrict__ poscol,
    const int* __restrict__ gm, float* __restrict__ out) {
    const int n = threadIdx.x;  // 1024
    const int g = gm[n];
    const float pos = posv[n];
    const float sum_neg = colsum[g] - poscol[g];
    const float cl = -logf(pos / (pos + sum_neg + EPS) + EPS);
    float v = rowloss[n] + cl;
    v = waveSum(v);
    __shared__ float red[16];
    if ((n & 63) == 0) red[n >> 6] = v;
    __syncthreads();
    if (n == 0) {
        float s = 0.f;
#pragma unroll
        for (int i = 0; i < 16; i++) s += red[i];
        out[0] = s / (2.f * NN);
    }
}

extern "C" void kernel_launch(void* const* d_in, const int* in_sizes, int n_in,
                              void* d_out, int out_size, void* d_ws, size_t ws_size,
                              hipStream_t stream) {
    const float* text = (const float*)d_in[0];
    const float* vis = (const float*)d_in[1];
    const int* gm = (const int*)d_in[2];
    const float* gamma = (const float*)d_in[3];
    const float* beta = (const float*)d_in[4];
    const float* logtemp = (const float*)d_in[5];
    float* out = (float*)d_out;

    float* ws = (float*)d_ws;
    float* tf = ws;                                   // N*D
    float* qinv = tf + (size_t)NN * DD;               // N
    float* vt = qinv + NN;                            // B*L*D
    float* attn = vt + (size_t)BB * LL * DD;          // B*N*L
    float* logits = attn + (size_t)BB * NN * LL;      // N*B
    float* scaled = logits + (size_t)NN * BB;         // N*B
    float* posv = scaled + (size_t)NN * BB;           // N
    float* rowloss = posv + NN;                       // N
    float* colsum = rowloss + NN;                     // B
    float* poscol = colsum + BB;                      // B

    ln_kernel<<<NN, 256, 0, stream>>>(text, tf, gamma, beta, qinv);
    ln_kernel<<<BB * LL, 256, 0, stream>>>(vis, vt, gamma, beta, nullptr);

    dim3 gs(NN / NT, BB);
    scores_kernel<<<gs, 256, 0, stream>>>(tf, vt, attn);
    agg_kernel<<<gs, 256, 0, stream>>>(tf, vt, attn, qinv, logits);

    loss_row_kernel<<<NN, 64, 0, stream>>>(logits, gm, logtemp, scaled, posv, rowloss);
    colsum_kernel<<<BB, 256, 0, stream>>>(scaled, gm, colsum, poscol);
    final_kernel<<<1, 1024, 0, stream>>>(posv, rowloss, colsum, poscol, gm, out);
}

// Round 3
// 263.252 us; speedup vs baseline: 5.3884x; 5.3884x over previous
//
#include <hip/hip_runtime.h>
#include <hip/hip_bf16.h>
#include <math.h>

#define NN 1024
#define BB 64
#define LL 197
#define LP 224
#define DD 768

typedef __attribute__((ext_vector_type(8))) short short8;
typedef __attribute__((ext_vector_type(4))) float f32x4;

constexpr float LN_EPS = 1e-5f;
constexpr float NORM_EPS = 1e-12f;
constexpr float EPS = 1e-8f;

__device__ __forceinline__ float waveSum(float v) {
#pragma unroll
    for (int m = 32; m >= 1; m >>= 1) v += __shfl_xor(v, m, 64);
    return v;
}
// reduce across the 16 lanes of a column group (lane&15 varies)
__device__ __forceinline__ float grpSum(float v) {
#pragma unroll
    for (int m = 8; m >= 1; m >>= 1) v += __shfl_xor(v, m, 64);
    return v;
}
__device__ __forceinline__ float grpMax(float v) {
#pragma unroll
    for (int m = 8; m >= 1; m >>= 1) v = fmaxf(v, __shfl_xor(v, m, 64));
    return v;
}

__device__ __forceinline__ unsigned short f2bf(float f) {
    __hip_bfloat16 h = __float2bfloat16(f);
    return reinterpret_cast<unsigned short&>(h);
}

// Row LayerNorm -> bf16 out. lmod>0: out row = (row/lmod)*LP + row%lmod (vision pad layout).
// qinv != nullptr: store 1/max(||y_bf16||,eps).
__global__ __launch_bounds__(256) void ln_kernel(
    const float* __restrict__ x, __hip_bfloat16* __restrict__ y,
    const float* __restrict__ gamma, const float* __restrict__ beta,
    float* __restrict__ qinv, int lmod) {
    const int row = blockIdx.x;
    const int tid = threadIdx.x;
    const float* xr = x + (size_t)row * DD;
    const int orow = (lmod > 0) ? (row / lmod) * LP + row % lmod : row;
    __hip_bfloat16* yr = y + (size_t)orow * DD;

    float v[3];
    float s = 0.f, ss = 0.f;
#pragma unroll
    for (int c = 0; c < 3; c++) {
        float t = xr[tid + 256 * c];
        v[c] = t; s += t; ss += t * t;
    }
    __shared__ float red[8];
    s = waveSum(s); ss = waveSum(ss);
    const int w = tid >> 6;
    if ((tid & 63) == 0) { red[w] = s; red[4 + w] = ss; }
    __syncthreads();
    s = red[0] + red[1] + red[2] + red[3];
    ss = red[4] + red[5] + red[6] + red[7];
    const float mean = s * (1.f / DD);
    const float var = ss * (1.f / DD) - mean * mean;
    const float rs = rsqrtf(var + LN_EPS);

    float q = 0.f;
#pragma unroll
    for (int c = 0; c < 3; c++) {
        const int d = tid + 256 * c;
        float t = (v[c] - mean) * rs * gamma[d] + beta[d];
        __hip_bfloat16 hb = __float2bfloat16(t);
        yr[d] = hb;
        float tb = __bfloat162float(hb);
        q += tb * tb;
    }
    if (qinv != nullptr) {
        __syncthreads();
        q = waveSum(q);
        if ((tid & 63) == 0) red[w] = q;
        __syncthreads();
        if (tid == 0) {
            float n2 = red[0] + red[1] + red[2] + red[3];
            qinv[row] = 1.f / fmaxf(sqrtf(n2), NORM_EPS);
        }
    }
}

// G[b] = vt_b . vt_b^T  [LP x LP] bf16. Grid (14, 64): x=row-block, y=b.
__global__ __launch_bounds__(256) void gram_kernel(
    const __hip_bfloat16* __restrict__ vt, __hip_bfloat16* __restrict__ G) {
    const int rb = blockIdx.x, b = blockIdx.y;
    const int tid = threadIdx.x, w = tid >> 6, lane = tid & 63;
    const short* vtb = (const short*)(vt + (size_t)b * LP * DD);
    const int kof = (lane >> 4) * 8;

    short8 a[24];
    const int arow = rb * 16 + (lane & 15);
#pragma unroll
    for (int ks = 0; ks < 24; ks++)
        a[ks] = *(const short8*)(vtb + (size_t)arow * DD + ks * 32 + kof);

    for (int cb = w; cb < 14; cb += 4) {
        f32x4 c = {0.f, 0.f, 0.f, 0.f};
        const int brow = cb * 16 + (lane & 15);
#pragma unroll
        for (int ks = 0; ks < 24; ks++) {
            short8 bf = *(const short8*)(vtb + (size_t)brow * DD + ks * 32 + kof);
            c = __builtin_amdgcn_mfma_f32_16x16x32_bf16(a[ks], bf, c, 0, 0, 0);
        }
        __hip_bfloat16* Gb = G + ((size_t)b * LP + rb * 16) * LP + cb * 16;
        const int col = lane & 15, rg = (lane >> 4) * 4;
#pragma unroll
        for (int r = 0; r < 4; r++) Gb[(size_t)(rg + r) * LP + col] = __float2bfloat16(c[r]);
    }
}

// Fused: S = tf.vt^T, softmax, num = sum P*Sraw, T = P.G, den = sum P*T, logits.
// Grid (16, 64): x = n-tile of 64, y = b. 4 waves, wave w owns rows n0+w*16..+15.
__global__ __launch_bounds__(256) void main_kernel(
    const __hip_bfloat16* __restrict__ tf, const __hip_bfloat16* __restrict__ vt,
    const __hip_bfloat16* __restrict__ G, const float* __restrict__ qinv,
    float* __restrict__ logits) {
    const int b = blockIdx.y;
    const int n0 = blockIdx.x * 64;
    const int tid = threadIdx.x, w = tid >> 6, lane = tid & 63;
    const int colg = lane & 15;
    const int kof = (lane >> 4) * 8;

    __shared__ __align__(16) unsigned char vts[16 * 1536];
    __shared__ __align__(16) unsigned short plds[4][16 * 232];

    const short* tfp = (const short*)tf;
    const short* vtb = (const short*)(vt + (size_t)b * LP * DD);

    // preload tf A-frags (row = lane&15 within wave tile)
    short8 a[24];
    {
        const int arow = n0 + w * 16 + colg;
#pragma unroll
        for (int ks = 0; ks < 24; ks++)
            a[ks] = *(const short8*)(tfp + (size_t)arow * DD + ks * 32 + kof);
    }

    // Stage 1: S frags over 14 l-blocks, K=768 via LDS-staged vt chunks
    f32x4 s[14];
#pragma unroll
    for (int f = 0; f < 14; f++) s[f] = {0.f, 0.f, 0.f, 0.f};

    const int kcol16 = (lane >> 4) * 16;  // byte offset of this lane's 16B within a 64B k-step
#pragma unroll
    for (int lc = 0; lc < 14; lc++) {
        __syncthreads();
        const char* src = (const char*)(vtb + (size_t)lc * 16 * DD);
#pragma unroll
        for (int i = 0; i < 6; i++) {
            const int byteoff = (i * 256 + tid) * 16;
            const int row = byteoff / 1536;
            const int colb = byteoff - row * 1536;
            const int phys = row * 1536 + (colb ^ ((row & 7) << 4));
            *(short8*)(vts + phys) = *(const short8*)(src + byteoff);
        }
        __syncthreads();
        f32x4 acc = s[lc];
        const int brow = colg;
#pragma unroll
        for (int ks = 0; ks < 24; ks++) {
            const int colb = ks * 64 + kcol16;
            const int phys = brow * 1536 + (colb ^ ((brow & 7) << 4));
            short8 bf = *(const short8*)(vts + phys);
            acc = __builtin_amdgcn_mfma_f32_16x16x32_bf16(a[ks], bf, acc, 0, 0, 0);
        }
        s[lc] = acc;
    }

    // Stage 2: softmax over l (rows = n). Per reg r the row is (lane>>4)*4+r.
    const float inv_sqrtD = 0.0360843918f;  // 1/sqrt(768)
    float m0[4] = {-1e30f, -1e30f, -1e30f, -1e30f};
#pragma unroll
    for (int f = 0; f < 14; f++) {
        const int l = f * 16 + colg;
        if (l < LL) {
#pragma unroll
            for (int r = 0; r < 4; r++) m0[r] = fmaxf(m0[r], s[f][r]);
        }
    }
#pragma unroll
    for (int r = 0; r < 4; r++) m0[r] = grpMax(m0[r]);

    float sum0[4] = {0.f, 0.f, 0.f, 0.f}, num0[4] = {0.f, 0.f, 0.f, 0.f};
#pragma unroll
    for (int f = 0; f < 14; f++) {
        const int l = f * 16 + colg;
#pragma unroll
        for (int r = 0; r < 4; r++) {
            const float raw = s[f][r];
            const float p = (l < LL) ? __expf((raw - m0[r]) * inv_sqrtD) : 0.f;
            num0[r] += p * raw;
            sum0[r] += p;
            s[f][r] = p;
        }
    }
    float invs[4];
#pragma unroll
    for (int r = 0; r < 4; r++) {
        sum0[r] = grpSum(sum0[r]);
        num0[r] = grpSum(num0[r]);
        invs[r] = 1.f / sum0[r];
    }

    // normalize P and repack to LDS row-major [16][232]
#pragma unroll
    for (int f = 0; f < 14; f++) {
#pragma unroll
        for (int r = 0; r < 4; r++) {
            const float p = s[f][r] * invs[r];
            s[f][r] = p;
            plds[w][(size_t)((lane >> 4) * 4 + r) * 232 + f * 16 + colg] = f2bf(p);
        }
    }
    __syncthreads();

    // Stage 3: T = P . G  (K = 224 over l', G symmetric so B reads rows of G)
    f32x4 t[14];
#pragma unroll
    for (int f = 0; f < 14; f++) t[f] = {0.f, 0.f, 0.f, 0.f};
    const unsigned short* pl = plds[w];
    const short* Gb = (const short*)(G + (size_t)b * LP * LP);
#pragma unroll
    for (int kb = 0; kb < 7; kb++) {
        short8 pa = *(const short8*)(pl + (size_t)colg * 232 + kb * 32 + kof);
#pragma unroll
        for (int lb = 0; lb < 14; lb++) {
            short8 gb = *(const short8*)(Gb + (size_t)(lb * 16 + colg) * LP + kb * 32 + kof);
            t[lb] = __builtin_amdgcn_mfma_f32_16x16x32_bf16(pa, gb, t[lb], 0, 0, 0);
        }
    }

    // Stage 4: den = sum_l P*T, logits
    float den0[4] = {0.f, 0.f, 0.f, 0.f};
#pragma unroll
    for (int f = 0; f < 14; f++) {
#pragma unroll
        for (int r = 0; r < 4; r++) den0[r] += s[f][r] * t[f][r];
    }
#pragma unroll
    for (int r = 0; r < 4; r++) den0[r] = grpSum(den0[r]);

    if (colg == 0) {
#pragma unroll
        for (int r = 0; r < 4; r++) {
            const int n = n0 + w * 16 + (lane >> 4) * 4 + r;
            const float num = num0[r] * invs[r];  // = tf . aggregated  (raw dots)
            const float den = fmaxf(sqrtf(fmaxf(den0[r], 0.f)), NORM_EPS);
            logits[(size_t)n * BB + b] = num * qinv[n] / den;
        }
    }
}

__global__ __launch_bounds__(64) void loss_row_kernel(
    const float* __restrict__ logits, const int* __restrict__ gm,
    const float* __restrict__ logtemp, float* __restrict__ scaled,
    float* __restrict__ posv, float* __restrict__ rowloss) {
    const int n = blockIdx.x;
    const int b = threadIdx.x;
    const float invtemp = 1.f / expf(logtemp[0]);
    const float e = expf(logits[(size_t)n * BB + b] * invtemp);
    scaled[(size_t)n * BB + b] = e;
    const float sum = waveSum(e);
    const int g = gm[n];
    const float pos = __shfl(e, g, 64);
    if (b == 0) {
        posv[n] = pos;
        rowloss[n] = -logf(pos / (sum + EPS) + EPS);
    }
}

__global__ __launch_bounds__(256) void colsum_kernel(
    const float* __restrict__ scaled, const int* __restrict__ gm,
    float* __restrict__ colsum, float* __restrict__ poscol) {
    const int b = blockIdx.x;
    const int tid = threadIdx.x;
    float s = 0.f, p = 0.f;
    for (int n = tid; n < NN; n += 256) {
        const float e = scaled[(size_t)n * BB + b];
        s += e;
        if (gm[n] == b) p += e;
    }
    s = waveSum(s); p = waveSum(p);
    __shared__ float red[8];
    const int w = tid >> 6;
    if ((tid & 63) == 0) { red[w] = s; red[4 + w] = p; }
    __syncthreads();
    if (tid == 0) {
        colsum[b] = red[0] + red[1] + red[2] + red[3];
        poscol[b] = red[4] + red[5] + red[6] + red[7];
    }
}

__global__ __launch_bounds__(1024) void final_kernel(
    const float* __restrict__ posv, const float* __restrict__ rowloss,
    const float* __restrict__ colsum, const float* __restrict__ poscol,
    const int* __restrict__ gm, float* __restrict__ out) {
    const int n = threadIdx.x;
    const int g = gm[n];
    const float pos = posv[n];
    const float sum_neg = colsum[g] - poscol[g];
    const float cl = -logf(pos / (pos + sum_neg + EPS) + EPS);
    float v = rowloss[n] + cl;
    v = waveSum(v);
    __shared__ float red[16];
    if ((n & 63) == 0) red[n >> 6] = v;
    __syncthreads();
    if (n == 0) {
        float s = 0.f;
#pragma unroll
        for (int i = 0; i < 16; i++) s += red[i];
        out[0] = s / (2.f * NN);
    }
}

extern "C" void kernel_launch(void* const* d_in, const int* in_sizes, int n_in,
                              void* d_out, int out_size, void* d_ws, size_t ws_size,
                              hipStream_t stream) {
    const float* text = (const float*)d_in[0];
    const float* vis = (const float*)d_in[1];
    const int* gm = (const int*)d_in[2];
    const float* gamma = (const float*)d_in[3];
    const float* beta = (const float*)d_in[4];
    const float* logtemp = (const float*)d_in[5];
    float* out = (float*)d_out;

    char* w = (char*)d_ws;
    __hip_bfloat16* tf = (__hip_bfloat16*)w;             w += (size_t)NN * DD * 2;      // 1.5 MB
    __hip_bfloat16* vt = (__hip_bfloat16*)w;             w += (size_t)BB * LP * DD * 2; // 22 MB
    __hip_bfloat16* G  = (__hip_bfloat16*)w;             w += (size_t)BB * LP * LP * 2; // 6.4 MB
    float* qinv    = (float*)w;  w += (size_t)NN * 4;
    float* logits  = (float*)w;  w += (size_t)NN * BB * 4;
    float* scaled  = (float*)w;  w += (size_t)NN * BB * 4;
    float* posv    = (float*)w;  w += (size_t)NN * 4;
    float* rowloss = (float*)w;  w += (size_t)NN * 4;
    float* colsum  = (float*)w;  w += (size_t)BB * 4;
    float* poscol  = (float*)w;  w += (size_t)BB * 4;

    hipMemsetAsync(vt, 0, (size_t)BB * LP * DD * 2, stream);  // zero pad rows

    ln_kernel<<<NN, 256, 0, stream>>>(text, tf, gamma, beta, qinv, 0);
    ln_kernel<<<BB * LL, 256, 0, stream>>>(vis, vt, gamma, beta, nullptr, LL);

    gram_kernel<<<dim3(14, BB), 256, 0, stream>>>(vt, G);
    main_kernel<<<dim3(NN / 64, BB), 256, 0, stream>>>(tf, vt, G, qinv, logits);

    loss_row_kernel<<<NN, 64, 0, stream>>>(logits, gm, logtemp, scaled, posv, rowloss);
    colsum_kernel<<<BB, 256, 0, stream>>>(scaled, gm, colsum, poscol);
    final_kernel<<<1, 1024, 0, stream>>>(posv, rowloss, colsum, poscol, gm, out);
}

// Round 4
// 248.163 us; speedup vs baseline: 5.7160x; 1.0608x over previous
//
#include <hip/hip_runtime.h>
#include <hip/hip_bf16.h>
#include <math.h>

#define NN 1024
#define BB 64
#define LL 197
#define LP 224
#define DD 768

typedef __attribute__((ext_vector_type(8))) short short8;
typedef __attribute__((ext_vector_type(4))) float f32x4;

constexpr float LN_EPS = 1e-5f;
constexpr float NORM_EPS = 1e-12f;
constexpr float EPS = 1e-8f;

__device__ __forceinline__ float waveSum(float v) {
#pragma unroll
    for (int m = 32; m >= 1; m >>= 1) v += __shfl_xor(v, m, 64);
    return v;
}
__device__ __forceinline__ float grpSum(float v) {
#pragma unroll
    for (int m = 8; m >= 1; m >>= 1) v += __shfl_xor(v, m, 64);
    return v;
}
__device__ __forceinline__ float grpMax(float v) {
#pragma unroll
    for (int m = 8; m >= 1; m >>= 1) v = fmaxf(v, __shfl_xor(v, m, 64));
    return v;
}

__device__ __forceinline__ unsigned short f2bf(float f) {
    __hip_bfloat16 h = __float2bfloat16(f);
    return reinterpret_cast<unsigned short&>(h);
}

__device__ __forceinline__ void gl_lds16(const void* g, void* l) {
    __builtin_amdgcn_global_load_lds(
        (const __attribute__((address_space(1))) unsigned int*)g,
        (__attribute__((address_space(3))) unsigned int*)l, 16, 0, 0);
}

// Text LayerNorm -> bf16 + qinv = 1/max(||y||,eps)
__global__ __launch_bounds__(256) void ln_kernel(
    const float* __restrict__ x, __hip_bfloat16* __restrict__ y,
    const float* __restrict__ gamma, const float* __restrict__ beta,
    float* __restrict__ qinv) {
    const int row = blockIdx.x;
    const int tid = threadIdx.x;
    const float* xr = x + (size_t)row * DD;
    __hip_bfloat16* yr = y + (size_t)row * DD;

    float v[3];
    float s = 0.f, ss = 0.f;
#pragma unroll
    for (int c = 0; c < 3; c++) {
        float t = xr[tid + 256 * c];
        v[c] = t; s += t; ss += t * t;
    }
    __shared__ float red[8];
    s = waveSum(s); ss = waveSum(ss);
    const int w = tid >> 6;
    if ((tid & 63) == 0) { red[w] = s; red[4 + w] = ss; }
    __syncthreads();
    s = red[0] + red[1] + red[2] + red[3];
    ss = red[4] + red[5] + red[6] + red[7];
    const float mean = s * (1.f / DD);
    const float var = ss * (1.f / DD) - mean * mean;
    const float rs = rsqrtf(var + LN_EPS);

    float q = 0.f;
#pragma unroll
    for (int c = 0; c < 3; c++) {
        const int d = tid + 256 * c;
        float t = (v[c] - mean) * rs * gamma[d] + beta[d];
        __hip_bfloat16 hb = __float2bfloat16(t);
        yr[d] = hb;
        float tb = __bfloat162float(hb);
        q += tb * tb;
    }
    __syncthreads();
    q = waveSum(q);
    if ((tid & 63) == 0) red[w] = q;
    __syncthreads();
    if (tid == 0) {
        float n2 = red[0] + red[1] + red[2] + red[3];
        qinv[row] = 1.f / fmaxf(sqrtf(n2), NORM_EPS);
    }
}

// Vision LayerNorm into padded [B, LP, D] layout; pad rows (l>=LL) zero-filled.
__global__ __launch_bounds__(256) void ln_vis_kernel(
    const float* __restrict__ x, __hip_bfloat16* __restrict__ y,
    const float* __restrict__ gamma, const float* __restrict__ beta) {
    const int id = blockIdx.x;
    const int b = id / LP, l = id - b * LP;
    const int tid = threadIdx.x;
    __hip_bfloat16* yr = y + ((size_t)b * LP + l) * DD;
    if (l >= LL) {
#pragma unroll
        for (int c = 0; c < 3; c++) yr[tid + 256 * c] = __float2bfloat16(0.f);
        return;
    }
    const float* xr = x + ((size_t)b * LL + l) * DD;

    float v[3];
    float s = 0.f, ss = 0.f;
#pragma unroll
    for (int c = 0; c < 3; c++) {
        float t = xr[tid + 256 * c];
        v[c] = t; s += t; ss += t * t;
    }
    __shared__ float red[8];
    s = waveSum(s); ss = waveSum(ss);
    const int w = tid >> 6;
    if ((tid & 63) == 0) { red[w] = s; red[4 + w] = ss; }
    __syncthreads();
    s = red[0] + red[1] + red[2] + red[3];
    ss = red[4] + red[5] + red[6] + red[7];
    const float mean = s * (1.f / DD);
    const float var = ss * (1.f / DD) - mean * mean;
    const float rs = rsqrtf(var + LN_EPS);
#pragma unroll
    for (int c = 0; c < 3; c++) {
        const int d = tid + 256 * c;
        yr[d] = __float2bfloat16((v[c] - mean) * rs * gamma[d] + beta[d]);
    }
}

// G[b] = vt_b . vt_b^T  [LP x LP] bf16. Grid (14, 64).
__global__ __launch_bounds__(256) void gram_kernel(
    const __hip_bfloat16* __restrict__ vt, __hip_bfloat16* __restrict__ G) {
    const int rb = blockIdx.x, b = blockIdx.y;
    const int tid = threadIdx.x, w = tid >> 6, lane = tid & 63;
    const short* vtb = (const short*)(vt + (size_t)b * LP * DD);
    const int kof = (lane >> 4) * 8;

    short8 a[24];
    const int arow = rb * 16 + (lane & 15);
#pragma unroll
    for (int ks = 0; ks < 24; ks++)
        a[ks] = *(const short8*)(vtb + (size_t)arow * DD + ks * 32 + kof);

    for (int cb = w; cb < 14; cb += 4) {
        f32x4 c = {0.f, 0.f, 0.f, 0.f};
        const int brow = cb * 16 + (lane & 15);
#pragma unroll
        for (int ks = 0; ks < 24; ks++) {
            short8 bf = *(const short8*)(vtb + (size_t)brow * DD + ks * 32 + kof);
            c = __builtin_amdgcn_mfma_f32_16x16x32_bf16(a[ks], bf, c, 0, 0, 0);
        }
        __hip_bfloat16* Gb = G + ((size_t)b * LP + rb * 16) * LP + cb * 16;
        const int col = lane & 15, rg = (lane >> 4) * 4;
#pragma unroll
        for (int r = 0; r < 4; r++) Gb[(size_t)(rg + r) * LP + col] = __float2bfloat16(c[r]);
    }
}

// Fused: S = tf.vt^T, softmax, num = sum P*Sraw, T = P.G, den = sum P*T, logits.
// Grid (16, 64). 4 waves, wave w owns rows n0+w*16..+15.
// LDS: 2 x 24KB vt chunk double-buffer; plds overlays buffer 0 after stage 1.
__global__ __launch_bounds__(256) void main_kernel(
    const __hip_bfloat16* __restrict__ tf, const __hip_bfloat16* __restrict__ vt,
    const __hip_bfloat16* __restrict__ G, const float* __restrict__ qinv,
    float* __restrict__ logits) {
    const int b = blockIdx.y;
    const int n0 = blockIdx.x * 64;
    const int tid = threadIdx.x, w = tid >> 6, lane = tid & 63;
    const int colg = lane & 15;
    const int kof = (lane >> 4) * 8;

    __shared__ __align__(16) unsigned char smem[49152];
    unsigned short* plds = (unsigned short*)smem;  // [4][16*232] = 29696 B, used post-stage1

    const short* tfp = (const short*)tf;
    const char* vtbc = (const char*)(vt + (size_t)b * LP * DD);

    // preload tf A-frags
    short8 a[24];
    {
        const int arow = n0 + w * 16 + colg;
#pragma unroll
        for (int ks = 0; ks < 24; ks++)
            a[ks] = *(const short8*)(tfp + (size_t)arow * DD + ks * 32 + kof);
    }

    // stage chunk lc (16 l-rows, 24KB) into buf via global_load_lds.
    // LDS is linear; source address carries the inverse XOR swizzle (involution).
    const int wbase = w * 6144;
#define STAGE(lc, buf)                                                          \
    {                                                                           \
        const char* src_ = vtbc + (size_t)(lc) * 16 * 1536;                     \
        _Pragma("unroll")                                                       \
        for (int i_ = 0; i_ < 6; i_++) {                                        \
            const int o_ = wbase + i_ * 1024 + lane * 16;                       \
            const int q_ = o_ >> 9;                                            \
            const int row_ = (q_ * 21846) >> 16;                                \
            const int cb_ = o_ - row_ * 1536;                                   \
            const int so_ = row_ * 1536 + (cb_ ^ ((row_ & 7) << 4));            \
            gl_lds16(src_ + so_, (buf) + wbase + i_ * 1024);                    \
        }                                                                       \
    }

    f32x4 s[14];
#pragma unroll
    for (int f = 0; f < 14; f++) s[f] = {0.f, 0.f, 0.f, 0.f};

    const int kcol16 = (lane >> 4) * 16;
    const int rswz = (colg & 7) << 4;
    const int rbase = colg * 1536;

    STAGE(0, smem);
    asm volatile("s_waitcnt vmcnt(0)" ::: "memory");
    __syncthreads();

#pragma unroll
    for (int lc = 0; lc < 14; lc++) {
        if (lc < 13) {
            if ((lc & 1) == 0) STAGE(lc + 1, smem + 24576)
            else               STAGE(lc + 1, smem)
        }
        const unsigned char* vb = smem + ((lc & 1) ? 24576 : 0);
        f32x4 acc = s[lc];
#pragma unroll
        for (int ks = 0; ks < 24; ks++) {
            const int phys = rbase + ((ks * 64 + kcol16) ^ rswz);
            short8 bf = *(const short8*)(vb + phys);
            acc = __builtin_amdgcn_mfma_f32_16x16x32_bf16(a[ks], bf, acc, 0, 0, 0);
        }
        s[lc] = acc;
        asm volatile("s_waitcnt vmcnt(0)" ::: "memory");
        __syncthreads();
    }
#undef STAGE

    // Stage 2: softmax over l. Row of reg r = (lane>>4)*4+r; col l = f*16+colg.
    const float inv_sqrtD = 0.0360843918f;
    float m0[4] = {-1e30f, -1e30f, -1e30f, -1e30f};
#pragma unroll
    for (int f = 0; f < 14; f++) {
        const int l = f * 16 + colg;
        if (l < LL) {
#pragma unroll
            for (int r = 0; r < 4; r++) m0[r] = fmaxf(m0[r], s[f][r]);
        }
    }
#pragma unroll
    for (int r = 0; r < 4; r++) m0[r] = grpMax(m0[r]);

    float sum0[4] = {0.f, 0.f, 0.f, 0.f}, num0[4] = {0.f, 0.f, 0.f, 0.f};
#pragma unroll
    for (int f = 0; f < 14; f++) {
        const int l = f * 16 + colg;
#pragma unroll
        for (int r = 0; r < 4; r++) {
            const float raw = s[f][r];
            const float p = (l < LL) ? __expf((raw - m0[r]) * inv_sqrtD) : 0.f;
            num0[r] += p * raw;
            sum0[r] += p;
            s[f][r] = p;
        }
    }
    float invs[4];
#pragma unroll
    for (int r = 0; r < 4; r++) {
        sum0[r] = grpSum(sum0[r]);
        num0[r] = grpSum(num0[r]);
        invs[r] = 1.f / sum0[r];
    }

    // normalize P; repack to per-wave LDS [16][232] (same-wave produce/consume)
#pragma unroll
    for (int f = 0; f < 14; f++) {
#pragma unroll
        for (int r = 0; r < 4; r++) {
            const float p = s[f][r] * invs[r];
            s[f][r] = p;
            plds[(size_t)w * 3712 + (size_t)((lane >> 4) * 4 + r) * 232 + f * 16 + colg] = f2bf(p);
        }
    }

    // Stage 3: T = P . G (K=224; G symmetric -> B-frags read G rows from L2)
    f32x4 t[14];
#pragma unroll
    for (int f = 0; f < 14; f++) t[f] = {0.f, 0.f, 0.f, 0.f};
    const unsigned short* pl = plds + (size_t)w * 3712;
    const short* Gb = (const short*)(G + (size_t)b * LP * LP);
#pragma unroll
    for (int kb = 0; kb < 7; kb++) {
        short8 pa = *(const short8*)(pl + (size_t)colg * 232 + kb * 32 + kof);
#pragma unroll
        for (int lb = 0; lb < 14; lb++) {
            short8 gb = *(const short8*)(Gb + (size_t)(lb * 16 + colg) * LP + kb * 32 + kof);
            t[lb] = __builtin_amdgcn_mfma_f32_16x16x32_bf16(pa, gb, t[lb], 0, 0, 0);
        }
    }

    // Stage 4: den = sum_l P*T, logits
    float den0[4] = {0.f, 0.f, 0.f, 0.f};
#pragma unroll
    for (int f = 0; f < 14; f++) {
#pragma unroll
        for (int r = 0; r < 4; r++) den0[r] += s[f][r] * t[f][r];
    }
#pragma unroll
    for (int r = 0; r < 4; r++) den0[r] = grpSum(den0[r]);

    if (colg == 0) {
#pragma unroll
        for (int r = 0; r < 4; r++) {
            const int n = n0 + w * 16 + (lane >> 4) * 4 + r;
            const float num = num0[r] * invs[r];
            const float den = fmaxf(sqrtf(fmaxf(den0[r], 0.f)), NORM_EPS);
            logits[(size_t)n * BB + b] = num * qinv[n] / den;
        }
    }
}

__global__ __launch_bounds__(64) void loss_row_kernel(
    const float* __restrict__ logits, const int* __restrict__ gm,
    const float* __restrict__ logtemp, float* __restrict__ scaled,
    float* __restrict__ posv, float* __restrict__ rowloss) {
    const int n = blockIdx.x;
    const int b = threadIdx.x;
    const float invtemp = 1.f / expf(logtemp[0]);
    const float e = expf(logits[(size_t)n * BB + b] * invtemp);
    scaled[(size_t)n * BB + b] = e;
    const float sum = waveSum(e);
    const int g = gm[n];
    const float pos = __shfl(e, g, 64);
    if (b == 0) {
        posv[n] = pos;
        rowloss[n] = -logf(pos / (sum + EPS) + EPS);
    }
}

__global__ __launch_bounds__(256) void colsum_kernel(
    const float* __restrict__ scaled, const int* __restrict__ gm,
    float* __restrict__ colsum, float* __restrict__ poscol) {
    const int b = blockIdx.x;
    const int tid = threadIdx.x;
    float s = 0.f, p = 0.f;
    for (int n = tid; n < NN; n += 256) {
        const float e = scaled[(size_t)n * BB + b];
        s += e;
        if (gm[n] == b) p += e;
    }
    s = waveSum(s); p = waveSum(p);
    __shared__ float red[8];
    const int w = tid >> 6;
    if ((tid & 63) == 0) { red[w] = s; red[4 + w] = p; }
    __syncthreads();
    if (tid == 0) {
        colsum[b] = red[0] + red[1] + red[2] + red[3];
        poscol[b] = red[4] + red[5] + red[6] + red[7];
    }
}

__global__ __launch_bounds__(1024) void final_kernel(
    const float* __restrict__ posv, const float* __restrict__ rowloss,
    const float* __restrict__ colsum, const float* __restrict__ poscol,
    const int* __restrict__ gm, float* __restrict__ out) {
    const int n = threadIdx.x;
    const int g = gm[n];
    const float pos = posv[n];
    const float sum_neg = colsum[g] - poscol[g];
    const float cl = -logf(pos / (pos + sum_neg + EPS) + EPS);
    float v = rowloss[n] + cl;
    v = waveSum(v);
    __shared__ float red[16];
    if ((n & 63) == 0) red[n >> 6] = v;
    __syncthreads();
    if (n == 0) {
        float s = 0.f;
#pragma unroll
        for (int i = 0; i < 16; i++) s += red[i];
        out[0] = s / (2.f * NN);
    }
}

extern "C" void kernel_launch(void* const* d_in, const int* in_sizes, int n_in,
                              void* d_out, int out_size, void* d_ws, size_t ws_size,
                              hipStream_t stream) {
    const float* text = (const float*)d_in[0];
    const float* vis = (const float*)d_in[1];
    const int* gm = (const int*)d_in[2];
    const float* gamma = (const float*)d_in[3];
    const float* beta = (const float*)d_in[4];
    const float* logtemp = (const float*)d_in[5];
    float* out = (float*)d_out;

    char* w = (char*)d_ws;
    __hip_bfloat16* tf = (__hip_bfloat16*)w;             w += (size_t)NN * DD * 2;
    __hip_bfloat16* vt = (__hip_bfloat16*)w;             w += (size_t)BB * LP * DD * 2;
    __hip_bfloat16* G  = (__hip_bfloat16*)w;             w += (size_t)BB * LP * LP * 2;
    float* qinv    = (float*)w;  w += (size_t)NN * 4;
    float* logits  = (float*)w;  w += (size_t)NN * BB * 4;
    float* scaled  = (float*)w;  w += (size_t)NN * BB * 4;
    float* posv    = (float*)w;  w += (size_t)NN * 4;
    float* rowloss = (float*)w;  w += (size_t)NN * 4;
    float* colsum  = (float*)w;  w += (size_t)BB * 4;
    float* poscol  = (float*)w;  w += (size_t)BB * 4;

    ln_kernel<<<NN, 256, 0, stream>>>(text, tf, gamma, beta, qinv);
    ln_vis_kernel<<<BB * LP, 256, 0, stream>>>(vis, vt, gamma, beta);

    gram_kernel<<<dim3(14, BB), 256, 0, stream>>>(vt, G);
    main_kernel<<<dim3(NN / 64, BB), 256, 0, stream>>>(tf, vt, G, qinv, logits);

    loss_row_kernel<<<NN, 64, 0, stream>>>(logits, gm, logtemp, scaled, posv, rowloss);
    colsum_kernel<<<BB, 256, 0, stream>>>(scaled, gm, colsum, poscol);
    final_kernel<<<1, 1024, 0, stream>>>(posv, rowloss, colsum, poscol, gm, out);
}